// Round 6
// baseline (161.694 us; speedup 1.0000x reference)
//
#include <hip/hip_runtime.h>
#include <hip/hip_bf16.h>

typedef __attribute__((ext_vector_type(8))) short short8;
typedef __attribute__((ext_vector_type(4))) float f32x4;

#define NEG_SLOPE 0.02f

static __device__ __forceinline__ unsigned short f2bf(float f) {
    unsigned int u = __float_as_uint(f);
    u += 0x7fffu + ((u >> 16) & 1u);
    return (unsigned short)(u >> 16);
}

// ---------------- prep: weight transforms ----------------
// wb[co][tap][ci]  bf16  (64*9*64)   from conv_w[co][ci][dy][dx]
// pwb[o][k] = bf16(pred_w[o][k]) for o<24, 0 pad to 32 rows  (32*768 bf16)
__global__ __launch_bounds__(256) void prep_kernel(const float* __restrict__ conv_w,
                                                   const float* __restrict__ pred_w,
                                                   unsigned short* __restrict__ wb,
                                                   unsigned short* __restrict__ pwb) {
    int i = blockIdx.x * 256 + threadIdx.x;
    if (i < 36864) {
        int ci = i & 63, tap = (i >> 6) % 9, co = i / 576;
        wb[i] = f2bf(conv_w[(co * 64 + ci) * 9 + tap]);
    }
    if (i < 24576) {
        int o = i / 768, k = i - o * 768;
        pwb[i] = f2bf(o < 24 ? pred_w[o * 768 + k] : 0.0f);
    }
}

// ---------------- NCHW f32 -> NHWC bf16 transpose (proven in round 4) ----------------
__global__ __launch_bounds__(256) void nchw2nhwc(const float* __restrict__ x,
                                                 unsigned short* __restrict__ xh) {
    __shared__ float t[64 * 132];
    const int bid = blockIdx.x;              // 32 b * 128 row-tiles
    const int b = bid >> 7, tile = bid & 127;
    const float* xb = x + ((size_t)b << 20) + tile * 128;
    const int tid = threadIdx.x;

    for (int j = tid; j < 2048; j += 256) {
        int ci = j >> 5, f4 = j & 31;
        float4 v = *(const float4*)(xb + (size_t)ci * 16384 + f4 * 4);
        *(float4*)&t[ci * 132 + f4 * 4] = v;
    }
    __syncthreads();

    const int px = tid >> 1, half = tid & 1;
    const float* col = t + (half * 32) * 132 + px;
    unsigned int o[16];
#pragma unroll
    for (int d = 0; d < 16; ++d) {
        float f0 = col[(2 * d) * 132];
        float f1 = col[(2 * d + 1) * 132];
        o[d] = (unsigned int)f2bf(f0) | ((unsigned int)f2bf(f1) << 16);
    }
    unsigned short* dst = xh + ((size_t)(b * 16384 + tile * 128 + px)) * 64 + half * 32;
#pragma unroll
    for (int d = 0; d < 4; ++d)
        *(uint4*)(dst + d * 8) = *(uint4*)&o[d * 4];
}

// ---------------- conv 3x3 + bias + leaky relu: 9-tap GEMM, A direct from global ----------------
// block: 2 output rows x 128 px x 64 co; 4 waves, wave = 64 px x 64 co (4m x 4n).
// Weights staged ONCE to LDS (full K), single barrier; K-loop = 9 taps x 2 ci-chunks,
// A-frags = 16B global loads from NHWC (L1/L2-cached, taps re-read), no input LDS.
// w_sm row stride 584 elems -> B-frag b128 read hits every bank exactly 8 dwords: conflict-free.
#define WROW 584
__global__ __launch_bounds__(256) void conv_mfma(const unsigned short* __restrict__ xh,
                                                 const unsigned short* __restrict__ wb,
                                                 const float* __restrict__ cb,
                                                 unsigned short* __restrict__ h) {
    __shared__ unsigned short w_sm[64 * WROW];   // 74,752 B

    // XCD-chunked swizzle: contiguous (b, y-pair) chunks per XCD
    const int id = blockIdx.x;
    const int xcd = id & 7, local = id >> 3;
    const int b = local & 31;
    const int y0 = ((xcd << 3) + (local >> 5)) * 2;

    const int tid = threadIdx.x;
    for (int j = tid; j < 4608; j += 256) {      // 64 co rows x 72 uint4
        int co = j / 72, c = j % 72;
        *(uint4*)(w_sm + co * WROW + c * 8) = *(const uint4*)(wb + co * 576 + c * 8);
    }
    __syncthreads();

    const int wave = tid >> 6, lane = tid & 63;
    const int lr = lane & 15, kg = lane >> 4;
    const int ro = wave >> 1;                    // output row within block
    const int px0 = (wave & 1) * 64;             // px half
    const int y = y0 + ro;

    f32x4 acc[4][4];
#pragma unroll
    for (int m = 0; m < 4; ++m)
#pragma unroll
        for (int n = 0; n < 4; ++n) acc[m][n] = (f32x4){0.f, 0.f, 0.f, 0.f};

    const unsigned short* bb[4];
#pragma unroll
    for (int n = 0; n < 4; ++n) bb[n] = w_sm + (n * 16 + lr) * WROW + kg * 8;

    const short8 z8 = {0, 0, 0, 0, 0, 0, 0, 0};
    const unsigned short* xb = xh + ((size_t)b << 14) * 64;   // [y][x][ci]

#pragma unroll
    for (int t = 0; t < 9; ++t) {
        const int dy = t / 3, dx = t % 3;
        const int gy = y + dy - 1;
        short8 A[4][2];
        if ((unsigned)gy < 128u) {
            const unsigned short* rowp = xb + ((size_t)gy << 7) * 64 + kg * 8;
#pragma unroll
            for (int m = 0; m < 4; ++m) {
                int gx = px0 + m * 16 + lr + dx - 1;
                const unsigned short* p = rowp + (gx & 127) * 64;
                bool ok = (unsigned)gx < 128u;
                short8 v0 = *(const short8*)p;
                short8 v1 = *(const short8*)(p + 32);
                A[m][0] = ok ? v0 : z8;
                A[m][1] = ok ? v1 : z8;
            }
        } else {
#pragma unroll
            for (int m = 0; m < 4; ++m) { A[m][0] = z8; A[m][1] = z8; }
        }
#pragma unroll
        for (int n = 0; n < 4; ++n) {
            short8 B0 = *(const short8*)(bb[n] + t * 64);
            short8 B1 = *(const short8*)(bb[n] + t * 64 + 32);
#pragma unroll
            for (int m = 0; m < 4; ++m) {
                acc[m][n] = __builtin_amdgcn_mfma_f32_16x16x32_bf16(A[m][0], B0, acc[m][n], 0, 0, 0);
                acc[m][n] = __builtin_amdgcn_mfma_f32_16x16x32_bf16(A[m][1], B1, acc[m][n], 0, 0, 0);
            }
        }
    }

    // ---- epilogue: bias + leaky relu, bf16 NHWC store ----
    float bias[4];
#pragma unroll
    for (int n = 0; n < 4; ++n) bias[n] = cb[n * 16 + lr];
    const size_t hrow = (size_t)(b * 128 + y) * 128;
#pragma unroll
    for (int m = 0; m < 4; ++m)
#pragma unroll
        for (int rr = 0; rr < 4; ++rr) {
            const int p = px0 + m * 16 + kg * 4 + rr;
            unsigned short* hp = h + (hrow + p) * 64 + lr;
#pragma unroll
            for (int n = 0; n < 4; ++n) {
                float v = acc[m][n][rr] + bias[n];
                v = v > 0.0f ? v : NEG_SLOPE * v;
                hp[n * 16] = f2bf(v);
            }
        }
}

// ---------------- gather + (pairs x 768)·(768 x 24) GEMM via MFMA ----------------
__global__ __launch_bounds__(256) void gather_gemm(const unsigned short* __restrict__ h,
                                                   const int* __restrict__ pos,
                                                   const unsigned short* __restrict__ pw,
                                                   const float* __restrict__ pred_b,
                                                   float* __restrict__ out) {
    __shared__ unsigned char pw_lds[32 * 1536];   // 32 rows x 768 bf16, swizzled
    const int tid = threadIdx.x;

    for (int i = tid; i < 3072; i += 256) {       // 3072 chunks of 16B
        int row = i / 96, c = i - row * 96;
        int dst = row * 1536 + ((c * 16) ^ ((row & 7) << 4));
        *(uint4*)(pw_lds + dst) = ((const uint4*)pw)[i];
    }
    __syncthreads();

    const int wave = tid >> 6, lane = tid & 63;
    const int pair_base = blockIdx.x * 64 + wave * 16;
    const int prow = lane & 15;
    const int kgrp = lane >> 4;
    const int pair = pair_base + prow;
    const int b = pair & 31;
    const unsigned short* hb = h + (size_t)b * 16384 * 64;

    const int swz0 = (prow & 7) << 4;
    const unsigned char* bro0 = pw_lds + prow * 1536;
    const unsigned char* bro1 = pw_lds + (prow + 16) * 1536;

    f32x4 acc0 = {0.f, 0.f, 0.f, 0.f};
    f32x4 acc1 = {0.f, 0.f, 0.f, 0.f};

#pragma unroll
    for (int l = 0; l < 12; ++l) {
        int2 pq = ((const int2*)pos)[pair * 12 + l];
        int px = pq.x < 0 ? 0 : (pq.x > 127 ? 127 : pq.x);
        int py = pq.y < 0 ? 0 : (pq.y > 127 ? 127 : pq.y);
        const unsigned short* pix = hb + (((size_t)py << 7) + px) * 64;
#pragma unroll
        for (int half = 0; half < 2; ++half) {
            const int c0 = half * 32 + kgrp * 8;
            short8 a = *(const short8*)(pix + c0);
            const int kb = (l * 64 + half * 32 + kgrp * 8) * 2;
            short8 b0 = *(const short8*)(bro0 + (kb ^ swz0));
            short8 b1 = *(const short8*)(bro1 + (kb ^ swz0));
            acc0 = __builtin_amdgcn_mfma_f32_16x16x32_bf16(a, b0, acc0, 0, 0, 0);
            acc1 = __builtin_amdgcn_mfma_f32_16x16x32_bf16(a, b1, acc1, 0, 0, 0);
        }
    }

    const int o0 = lane & 15;
    const float bias0 = pred_b[o0];
    const float bias1 = (o0 + 16 < 24) ? pred_b[o0 + 16] : 0.0f;
#pragma unroll
    for (int r = 0; r < 4; ++r) {
        const int pout = pair_base + (lane >> 4) * 4 + r;
        out[(size_t)pout * 24 + o0] = acc0[r] + bias0;
        if (o0 + 16 < 24)
            out[(size_t)pout * 24 + o0 + 16] = acc1[r] + bias1;
    }
}

extern "C" void kernel_launch(void* const* d_in, const int* in_sizes, int n_in,
                              void* d_out, int out_size, void* d_ws, size_t ws_size,
                              hipStream_t stream) {
    const float* x      = (const float*)d_in[0];
    const int*   pos    = (const int*)d_in[1];
    const float* conv_w = (const float*)d_in[2];
    const float* conv_b = (const float*)d_in[3];
    const float* pred_w = (const float*)d_in[4];
    const float* pred_b = (const float*)d_in[5];
    float* out = (float*)d_out;

    char* ws = (char*)d_ws;
    unsigned short* xh  = (unsigned short*)ws;                         // 67,108,864 B
    unsigned short* h   = (unsigned short*)(ws + 67108864);            // 67,108,864 B
    unsigned short* wb  = (unsigned short*)(ws + 134217728);           // 73,728 B
    unsigned short* pwb = (unsigned short*)(ws + 134217728 + 73728);   // 49,152 B

    prep_kernel<<<144, 256, 0, stream>>>(conv_w, pred_w, wb, pwb);
    nchw2nhwc<<<4096, 256, 0, stream>>>(x, xh);
    conv_mfma<<<2048, 256, 0, stream>>>(xh, wb, conv_b, h);
    gather_gemm<<<500, 256, 0, stream>>>(h, pos, pwb, pred_b, out);
}

// Round 7
// 160.352 us; speedup vs baseline: 1.0084x; 1.0084x over previous
//
#include <hip/hip_runtime.h>
#include <hip/hip_bf16.h>

typedef __attribute__((ext_vector_type(8))) short short8;
typedef __attribute__((ext_vector_type(4))) float f32x4;

#define NEG_SLOPE 0.02f

static __device__ __forceinline__ unsigned short f2bf(float f) {
    unsigned int u = __float_as_uint(f);
    u += 0x7fffu + ((u >> 16) & 1u);
    return (unsigned short)(u >> 16);
}

// ---------------- prep: weight transforms ----------------
// wb chunk-major: [cc][co][tap][ci32]  bf16  (2*64*9*32) from conv_w[co][ci][dy][dx]
// pwb[o][k] = bf16(pred_w[o][k]) for o<24, 0 pad to 32 rows  (32*768 bf16)
__global__ __launch_bounds__(256) void prep_kernel(const float* __restrict__ conv_w,
                                                   const float* __restrict__ pred_w,
                                                   unsigned short* __restrict__ wb,
                                                   unsigned short* __restrict__ pwb) {
    int i = blockIdx.x * 256 + threadIdx.x;
    if (i < 36864) {
        int ci5 = i & 31, tap = (i >> 5) % 9, rest = i / 288;  // rest = cc*64 + co
        int co = rest & 63, cc = rest >> 6;
        int ci = cc * 32 + ci5;
        wb[i] = f2bf(conv_w[(co * 64 + ci) * 9 + tap]);
    }
    if (i < 24576) {
        int o = i / 768, k = i - o * 768;
        pwb[i] = f2bf(o < 24 ? pred_w[o * 768 + k] : 0.0f);
    }
}

// ---------------- NCHW f32 -> NHWC bf16 transpose (proven) ----------------
__global__ __launch_bounds__(256) void nchw2nhwc(const float* __restrict__ x,
                                                 unsigned short* __restrict__ xh) {
    __shared__ float t[64 * 132];
    const int bid = blockIdx.x;              // 32 b * 128 row-tiles
    const int b = bid >> 7, tile = bid & 127;
    const float* xb = x + ((size_t)b << 20) + tile * 128;
    const int tid = threadIdx.x;

    for (int j = tid; j < 2048; j += 256) {
        int ci = j >> 5, f4 = j & 31;
        float4 v = *(const float4*)(xb + (size_t)ci * 16384 + f4 * 4);
        *(float4*)&t[ci * 132 + f4 * 4] = v;
    }
    __syncthreads();

    const int px = tid >> 1, half = tid & 1;
    const float* col = t + (half * 32) * 132 + px;
    unsigned int o[16];
#pragma unroll
    for (int d = 0; d < 16; ++d) {
        float f0 = col[(2 * d) * 132];
        float f1 = col[(2 * d + 1) * 132];
        o[d] = (unsigned int)f2bf(f0) | ((unsigned int)f2bf(f1) << 16);
    }
    unsigned short* dst = xh + ((size_t)(b * 16384 + tile * 128 + px)) * 64 + half * 32;
#pragma unroll
    for (int d = 0; d < 4; ++d)
        *(uint4*)(dst + d * 8) = *(uint4*)&o[d * 4];
}

// ---------------- conv 3x3 + bias + leaky relu: 9-tap GEMM, A direct from global ----------------
// block: 2 output rows x 128 px x 64 co; 4 waves, wave = 64 px x 64 co (4m x 4n).
// LDS = per-chunk weights ONLY (64co x 9tap x 32ci, stride 296) = 37,888 B -> 4 blocks/CU.
// K-loop per chunk: 9 taps, A-frags = one 16B NHWC global load each (L1/L2 cached),
// B-frags = ds_read_b128 (296-elem row stride -> conflict-light), 16 MFMA/tap. No
// barriers inside the tap loop -> compiler pipelines loads across taps.
__global__ __launch_bounds__(256) void conv_mfma(const unsigned short* __restrict__ xh,
                                                 const unsigned short* __restrict__ wb,
                                                 const float* __restrict__ cb,
                                                 unsigned short* __restrict__ h) {
    __shared__ unsigned short w_sm[64 * 296];    // 37,888 B

    // XCD-chunked swizzle: contiguous (b, y-pair) chunks per XCD
    const int id = blockIdx.x;
    const int xcd = id & 7, local = id >> 3;
    const int b = local & 31;
    const int y0 = ((xcd << 3) + (local >> 5)) * 2;

    const int tid = threadIdx.x;
    const int wave = tid >> 6, lane = tid & 63;
    const int lr = lane & 15, kg = lane >> 4;
    const int ro = wave >> 1;                    // output row within block
    const int px0 = (wave & 1) * 64;             // px half
    const int y = y0 + ro;

    f32x4 acc[4][4];
#pragma unroll
    for (int m = 0; m < 4; ++m)
#pragma unroll
        for (int n = 0; n < 4; ++n) acc[m][n] = (f32x4){0.f, 0.f, 0.f, 0.f};

    const unsigned short* bb[4];
#pragma unroll
    for (int n = 0; n < 4; ++n) bb[n] = w_sm + (n * 16 + lr) * 296 + kg * 8;

    const short8 z8 = {0, 0, 0, 0, 0, 0, 0, 0};

    for (int cc = 0; cc < 2; ++cc) {
        __syncthreads();
        // stage chunk-cc weights: source is contiguous (j*8), dest stride 296
        const unsigned short* wsrc = wb + cc * 18432;
        for (int j = tid; j < 2304; j += 256) {
            int q = j & 3, tap = (j >> 2) % 9, co = j / 36;
            *(uint4*)(w_sm + co * 296 + tap * 32 + q * 8) = *(const uint4*)(wsrc + j * 8);
        }
        __syncthreads();

        const unsigned short* xb = xh + (((size_t)b << 14)) * 64 + cc * 32 + kg * 8;

#pragma unroll
        for (int t = 0; t < 9; ++t) {
            const int dy = t / 3, dx = t % 3;
            const int gy = y + dy - 1;
            short8 A[4];
            if ((unsigned)gy < 128u) {
                const unsigned short* rowp = xb + ((size_t)gy << 13);
#pragma unroll
                for (int m = 0; m < 4; ++m) {
                    int gx = px0 + m * 16 + lr + dx - 1;
                    short8 v = *(const short8*)(rowp + (gx & 127) * 64);
                    A[m] = ((unsigned)gx < 128u) ? v : z8;
                }
            } else {
#pragma unroll
                for (int m = 0; m < 4; ++m) A[m] = z8;
            }
#pragma unroll
            for (int n = 0; n < 4; ++n) {
                short8 B = *(const short8*)(bb[n] + t * 32);
#pragma unroll
                for (int m = 0; m < 4; ++m)
                    acc[m][n] = __builtin_amdgcn_mfma_f32_16x16x32_bf16(A[m], B, acc[m][n], 0, 0, 0);
            }
        }
    }

    // ---- epilogue: bias + leaky relu, bf16 NHWC store ----
    float bias[4];
#pragma unroll
    for (int n = 0; n < 4; ++n) bias[n] = cb[n * 16 + lr];
    const size_t hrow = (size_t)(b * 128 + y) * 128;
#pragma unroll
    for (int m = 0; m < 4; ++m)
#pragma unroll
        for (int rr = 0; rr < 4; ++rr) {
            const int p = px0 + m * 16 + kg * 4 + rr;
            unsigned short* hp = h + (hrow + p) * 64 + lr;
#pragma unroll
            for (int n = 0; n < 4; ++n) {
                float v = acc[m][n][rr] + bias[n];
                v = v > 0.0f ? v : NEG_SLOPE * v;
                hp[n * 16] = f2bf(v);
            }
        }
}

// ---------------- gather + (pairs x 768)·(768 x 24) GEMM via MFMA ----------------
__global__ __launch_bounds__(256) void gather_gemm(const unsigned short* __restrict__ h,
                                                   const int* __restrict__ pos,
                                                   const unsigned short* __restrict__ pw,
                                                   const float* __restrict__ pred_b,
                                                   float* __restrict__ out) {
    __shared__ unsigned char pw_lds[32 * 1536];   // 32 rows x 768 bf16, swizzled
    const int tid = threadIdx.x;

    for (int i = tid; i < 3072; i += 256) {       // 3072 chunks of 16B
        int row = i / 96, c = i - row * 96;
        int dst = row * 1536 + ((c * 16) ^ ((row & 7) << 4));
        *(uint4*)(pw_lds + dst) = ((const uint4*)pw)[i];
    }
    __syncthreads();

    const int wave = tid >> 6, lane = tid & 63;
    const int pair_base = blockIdx.x * 64 + wave * 16;
    const int prow = lane & 15;
    const int kgrp = lane >> 4;
    const int pair = pair_base + prow;
    const int b = pair & 31;
    const unsigned short* hb = h + (size_t)b * 16384 * 64;

    const int swz0 = (prow & 7) << 4;
    const unsigned char* bro0 = pw_lds + prow * 1536;
    const unsigned char* bro1 = pw_lds + (prow + 16) * 1536;

    f32x4 acc0 = {0.f, 0.f, 0.f, 0.f};
    f32x4 acc1 = {0.f, 0.f, 0.f, 0.f};

#pragma unroll
    for (int l = 0; l < 12; ++l) {
        int2 pq = ((const int2*)pos)[pair * 12 + l];
        int px = pq.x < 0 ? 0 : (pq.x > 127 ? 127 : pq.x);
        int py = pq.y < 0 ? 0 : (pq.y > 127 ? 127 : pq.y);
        const unsigned short* pix = hb + (((size_t)py << 7) + px) * 64;
#pragma unroll
        for (int half = 0; half < 2; ++half) {
            const int c0 = half * 32 + kgrp * 8;
            short8 a = *(const short8*)(pix + c0);
            const int kb = (l * 64 + half * 32 + kgrp * 8) * 2;
            short8 b0 = *(const short8*)(bro0 + (kb ^ swz0));
            short8 b1 = *(const short8*)(bro1 + (kb ^ swz0));
            acc0 = __builtin_amdgcn_mfma_f32_16x16x32_bf16(a, b0, acc0, 0, 0, 0);
            acc1 = __builtin_amdgcn_mfma_f32_16x16x32_bf16(a, b1, acc1, 0, 0, 0);
        }
    }

    const int o0 = lane & 15;
    const float bias0 = pred_b[o0];
    const float bias1 = (o0 + 16 < 24) ? pred_b[o0 + 16] : 0.0f;
#pragma unroll
    for (int r = 0; r < 4; ++r) {
        const int pout = pair_base + (lane >> 4) * 4 + r;
        out[(size_t)pout * 24 + o0] = acc0[r] + bias0;
        if (o0 + 16 < 24)
            out[(size_t)pout * 24 + o0 + 16] = acc1[r] + bias1;
    }
}

extern "C" void kernel_launch(void* const* d_in, const int* in_sizes, int n_in,
                              void* d_out, int out_size, void* d_ws, size_t ws_size,
                              hipStream_t stream) {
    const float* x      = (const float*)d_in[0];
    const int*   pos    = (const int*)d_in[1];
    const float* conv_w = (const float*)d_in[2];
    const float* conv_b = (const float*)d_in[3];
    const float* pred_w = (const float*)d_in[4];
    const float* pred_b = (const float*)d_in[5];
    float* out = (float*)d_out;

    char* ws = (char*)d_ws;
    unsigned short* xh  = (unsigned short*)ws;                         // 67,108,864 B
    unsigned short* h   = (unsigned short*)(ws + 67108864);            // 67,108,864 B
    unsigned short* wb  = (unsigned short*)(ws + 134217728);           // 73,728 B
    unsigned short* pwb = (unsigned short*)(ws + 134217728 + 73728);   // 49,152 B

    prep_kernel<<<144, 256, 0, stream>>>(conv_w, pred_w, wb, pwb);
    nchw2nhwc<<<4096, 256, 0, stream>>>(x, xh);
    conv_mfma<<<2048, 256, 0, stream>>>(xh, wb, conv_b, h);
    gather_gemm<<<500, 256, 0, stream>>>(h, pos, pwb, pred_b, out);
}

// Round 8
// 152.257 us; speedup vs baseline: 1.0620x; 1.0532x over previous
//
#include <hip/hip_runtime.h>
#include <hip/hip_bf16.h>

typedef __attribute__((ext_vector_type(8))) short short8;
typedef __attribute__((ext_vector_type(4))) float f32x4;

#define NEG_SLOPE 0.02f

static __device__ __forceinline__ unsigned short f2bf(float f) {
    unsigned int u = __float_as_uint(f);
    u += 0x7fffu + ((u >> 16) & 1u);
    return (unsigned short)(u >> 16);
}

// ---------------- prep: weight transforms ----------------
// wb chunk-major: [cc][co][tap][ci32]  bf16  (2*64*9*32) from conv_w[co][ci][dy][dx]
// pwb[o][k] = bf16(pred_w[o][k]) for o<24, 0 pad to 32 rows  (32*768 bf16)
__global__ __launch_bounds__(256) void prep_kernel(const float* __restrict__ conv_w,
                                                   const float* __restrict__ pred_w,
                                                   unsigned short* __restrict__ wb,
                                                   unsigned short* __restrict__ pwb) {
    int i = blockIdx.x * 256 + threadIdx.x;
    if (i < 36864) {
        int ci5 = i & 31, tap = (i >> 5) % 9, rest = i / 288;  // rest = cc*64 + co
        int co = rest & 63, cc = rest >> 6;
        int ci = cc * 32 + ci5;
        wb[i] = f2bf(conv_w[(co * 64 + ci) * 9 + tap]);
    }
    if (i < 24576) {
        int o = i / 768, k = i - o * 768;
        pwb[i] = f2bf(o < 24 ? pred_w[o * 768 + k] : 0.0f);
    }
}

// ---------------- NCHW f32 -> NHWC bf16 transpose (proven) ----------------
__global__ __launch_bounds__(256) void nchw2nhwc(const float* __restrict__ x,
                                                 unsigned short* __restrict__ xh) {
    __shared__ float t[64 * 132];
    const int bid = blockIdx.x;              // 32 b * 128 row-tiles
    const int b = bid >> 7, tile = bid & 127;
    const float* xb = x + ((size_t)b << 20) + tile * 128;
    const int tid = threadIdx.x;

    for (int j = tid; j < 2048; j += 256) {
        int ci = j >> 5, f4 = j & 31;
        float4 v = *(const float4*)(xb + (size_t)ci * 16384 + f4 * 4);
        *(float4*)&t[ci * 132 + f4 * 4] = v;
    }
    __syncthreads();

    const int px = tid >> 1, half = tid & 1;
    const float* col = t + (half * 32) * 132 + px;
    unsigned int o[16];
#pragma unroll
    for (int d = 0; d < 16; ++d) {
        float f0 = col[(2 * d) * 132];
        float f1 = col[(2 * d + 1) * 132];
        o[d] = (unsigned int)f2bf(f0) | ((unsigned int)f2bf(f1) << 16);
    }
    unsigned short* dst = xh + ((size_t)(b * 16384 + tile * 128 + px)) * 64 + half * 32;
#pragma unroll
    for (int d = 0; d < 4; ++d)
        *(uint4*)(dst + d * 8) = *(uint4*)&o[d * 4];
}

// ---------------- conv 3x3 + bias + leaky relu: 9-tap GEMM, A direct from global ----------------
// block: ONE output row x 128 px x 64 co; 4 waves, wave = 32 px x 64 co (2m x 4n).
// acc[2][4]=32 regs + A[2]=8 -> total ~112 incl. addressing => 4 waves/SIMD.
// LDS = per-chunk weights only (stride 296) = 37,888 B. launch_bounds(256,4) pins regs.
__global__ __launch_bounds__(256, 4) void conv_mfma(const unsigned short* __restrict__ xh,
                                                    const unsigned short* __restrict__ wb,
                                                    const float* __restrict__ cb,
                                                    unsigned short* __restrict__ h) {
    __shared__ unsigned short w_sm[64 * 296];    // 37,888 B

    // XCD-chunked swizzle: each XCD gets 16 contiguous y rows x all b
    const int id = blockIdx.x;
    const int xcd = id & 7, local = id >> 3;
    const int b = local & 31;
    const int y = (xcd << 4) + (local >> 5);

    const int tid = threadIdx.x;
    const int wave = tid >> 6, lane = tid & 63;
    const int lr = lane & 15, kg = lane >> 4;
    const int px0 = wave * 32;

    f32x4 acc[2][4];
#pragma unroll
    for (int m = 0; m < 2; ++m)
#pragma unroll
        for (int n = 0; n < 4; ++n) acc[m][n] = (f32x4){0.f, 0.f, 0.f, 0.f};

    const unsigned short* bb[4];
#pragma unroll
    for (int n = 0; n < 4; ++n) bb[n] = w_sm + (n * 16 + lr) * 296 + kg * 8;

    const short8 z8 = {0, 0, 0, 0, 0, 0, 0, 0};

    for (int cc = 0; cc < 2; ++cc) {
        __syncthreads();
        // stage chunk-cc weights: source contiguous (j*8), dest stride 296
        const unsigned short* wsrc = wb + cc * 18432;
        for (int j = tid; j < 2304; j += 256) {
            int q = j & 3, tap = (j >> 2) % 9, co = j / 36;
            *(uint4*)(w_sm + co * 296 + tap * 32 + q * 8) = *(const uint4*)(wsrc + j * 8);
        }
        __syncthreads();

        const unsigned short* xb = xh + (((size_t)b << 14)) * 64 + cc * 32 + kg * 8;

#pragma unroll
        for (int t = 0; t < 9; ++t) {
            const int dy = t / 3, dx = t % 3;
            const int gy = y + dy - 1;
            short8 A[2];
            if ((unsigned)gy < 128u) {
                const unsigned short* rowp = xb + ((size_t)gy << 13);
#pragma unroll
                for (int m = 0; m < 2; ++m) {
                    int gx = px0 + m * 16 + lr + dx - 1;
                    short8 v = *(const short8*)(rowp + (gx & 127) * 64);
                    A[m] = ((unsigned)gx < 128u) ? v : z8;
                }
            } else {
#pragma unroll
                for (int m = 0; m < 2; ++m) A[m] = z8;
            }
#pragma unroll
            for (int n = 0; n < 4; ++n) {
                short8 B = *(const short8*)(bb[n] + t * 32);
#pragma unroll
                for (int m = 0; m < 2; ++m)
                    acc[m][n] = __builtin_amdgcn_mfma_f32_16x16x32_bf16(A[m], B, acc[m][n], 0, 0, 0);
            }
        }
    }

    // ---- epilogue: bias + leaky relu, bf16 NHWC store ----
    float bias[4];
#pragma unroll
    for (int n = 0; n < 4; ++n) bias[n] = cb[n * 16 + lr];
    const size_t hrow = (size_t)(b * 128 + y) * 128;
#pragma unroll
    for (int m = 0; m < 2; ++m)
#pragma unroll
        for (int rr = 0; rr < 4; ++rr) {
            const int p = px0 + m * 16 + kg * 4 + rr;
            unsigned short* hp = h + (hrow + p) * 64 + lr;
#pragma unroll
            for (int n = 0; n < 4; ++n) {
                float v = acc[m][n][rr] + bias[n];
                v = v > 0.0f ? v : NEG_SLOPE * v;
                hp[n * 16] = f2bf(v);
            }
        }
}

// ---------------- gather + (pairs x 768)·(768 x 24) GEMM via MFMA ----------------
__global__ __launch_bounds__(256) void gather_gemm(const unsigned short* __restrict__ h,
                                                   const int* __restrict__ pos,
                                                   const unsigned short* __restrict__ pw,
                                                   const float* __restrict__ pred_b,
                                                   float* __restrict__ out) {
    __shared__ unsigned char pw_lds[32 * 1536];   // 32 rows x 768 bf16, swizzled
    const int tid = threadIdx.x;

    for (int i = tid; i < 3072; i += 256) {       // 3072 chunks of 16B
        int row = i / 96, c = i - row * 96;
        int dst = row * 1536 + ((c * 16) ^ ((row & 7) << 4));
        *(uint4*)(pw_lds + dst) = ((const uint4*)pw)[i];
    }
    __syncthreads();

    const int wave = tid >> 6, lane = tid & 63;
    const int pair_base = blockIdx.x * 64 + wave * 16;
    const int prow = lane & 15;
    const int kgrp = lane >> 4;
    const int pair = pair_base + prow;
    const int b = pair & 31;
    const unsigned short* hb = h + (size_t)b * 16384 * 64;

    const int swz0 = (prow & 7) << 4;
    const unsigned char* bro0 = pw_lds + prow * 1536;
    const unsigned char* bro1 = pw_lds + (prow + 16) * 1536;

    f32x4 acc0 = {0.f, 0.f, 0.f, 0.f};
    f32x4 acc1 = {0.f, 0.f, 0.f, 0.f};

#pragma unroll
    for (int l = 0; l < 12; ++l) {
        int2 pq = ((const int2*)pos)[pair * 12 + l];
        int px = pq.x < 0 ? 0 : (pq.x > 127 ? 127 : pq.x);
        int py = pq.y < 0 ? 0 : (pq.y > 127 ? 127 : pq.y);
        const unsigned short* pix = hb + (((size_t)py << 7) + px) * 64;
#pragma unroll
        for (int half = 0; half < 2; ++half) {
            const int c0 = half * 32 + kgrp * 8;
            short8 a = *(const short8*)(pix + c0);
            const int kb = (l * 64 + half * 32 + kgrp * 8) * 2;
            short8 b0 = *(const short8*)(bro0 + (kb ^ swz0));
            short8 b1 = *(const short8*)(bro1 + (kb ^ swz0));
            acc0 = __builtin_amdgcn_mfma_f32_16x16x32_bf16(a, b0, acc0, 0, 0, 0);
            acc1 = __builtin_amdgcn_mfma_f32_16x16x32_bf16(a, b1, acc1, 0, 0, 0);
        }
    }

    const int o0 = lane & 15;
    const float bias0 = pred_b[o0];
    const float bias1 = (o0 + 16 < 24) ? pred_b[o0 + 16] : 0.0f;
#pragma unroll
    for (int r = 0; r < 4; ++r) {
        const int pout = pair_base + (lane >> 4) * 4 + r;
        out[(size_t)pout * 24 + o0] = acc0[r] + bias0;
        if (o0 + 16 < 24)
            out[(size_t)pout * 24 + o0 + 16] = acc1[r] + bias1;
    }
}

extern "C" void kernel_launch(void* const* d_in, const int* in_sizes, int n_in,
                              void* d_out, int out_size, void* d_ws, size_t ws_size,
                              hipStream_t stream) {
    const float* x      = (const float*)d_in[0];
    const int*   pos    = (const int*)d_in[1];
    const float* conv_w = (const float*)d_in[2];
    const float* conv_b = (const float*)d_in[3];
    const float* pred_w = (const float*)d_in[4];
    const float* pred_b = (const float*)d_in[5];
    float* out = (float*)d_out;

    char* ws = (char*)d_ws;
    unsigned short* xh  = (unsigned short*)ws;                         // 67,108,864 B
    unsigned short* h   = (unsigned short*)(ws + 67108864);            // 67,108,864 B
    unsigned short* wb  = (unsigned short*)(ws + 134217728);           // 73,728 B
    unsigned short* pwb = (unsigned short*)(ws + 134217728 + 73728);   // 49,152 B

    prep_kernel<<<144, 256, 0, stream>>>(conv_w, pred_w, wb, pwb);
    nchw2nhwc<<<4096, 256, 0, stream>>>(x, xh);
    conv_mfma<<<4096, 256, 0, stream>>>(xh, wb, conv_b, h);
    gather_gemm<<<500, 256, 0, stream>>>(h, pos, pwb, pred_b, out);
}

// Round 9
// 148.424 us; speedup vs baseline: 1.0894x; 1.0258x over previous
//
#include <hip/hip_runtime.h>
#include <hip/hip_bf16.h>

typedef __attribute__((ext_vector_type(8))) short short8;
typedef __attribute__((ext_vector_type(4))) float f32x4;

#define NEG_SLOPE 0.02f

static __device__ __forceinline__ unsigned short f2bf(float f) {
    unsigned int u = __float_as_uint(f);
    u += 0x7fffu + ((u >> 16) & 1u);
    return (unsigned short)(u >> 16);
}

// ---------------- prep: weight transforms ----------------
// wb chunk-major: [cc][co][tap][ci32]  bf16  (2*64*9*32) from conv_w[co][ci][dy][dx]
// pwb[o][k] = bf16(pred_w[o][k]) for o<24, 0 pad to 32 rows  (32*768 bf16)
__global__ __launch_bounds__(256) void prep_kernel(const float* __restrict__ conv_w,
                                                   const float* __restrict__ pred_w,
                                                   unsigned short* __restrict__ wb,
                                                   unsigned short* __restrict__ pwb) {
    int i = blockIdx.x * 256 + threadIdx.x;
    if (i < 36864) {
        int ci5 = i & 31, tap = (i >> 5) % 9, rest = i / 288;  // rest = cc*64 + co
        int co = rest & 63, cc = rest >> 6;
        int ci = cc * 32 + ci5;
        wb[i] = f2bf(conv_w[(co * 64 + ci) * 9 + tap]);
    }
    if (i < 24576) {
        int o = i / 768, k = i - o * 768;
        pwb[i] = f2bf(o < 24 ? pred_w[o * 768 + k] : 0.0f);
    }
}

// ---------------- NCHW f32 -> NHWC bf16 transpose (proven) ----------------
__global__ __launch_bounds__(256) void nchw2nhwc(const float* __restrict__ x,
                                                 unsigned short* __restrict__ xh) {
    __shared__ float t[64 * 132];
    const int bid = blockIdx.x;              // 32 b * 128 row-tiles
    const int b = bid >> 7, tile = bid & 127;
    const float* xb = x + ((size_t)b << 20) + tile * 128;
    const int tid = threadIdx.x;

    for (int j = tid; j < 2048; j += 256) {
        int ci = j >> 5, f4 = j & 31;
        float4 v = *(const float4*)(xb + (size_t)ci * 16384 + f4 * 4);
        *(float4*)&t[ci * 132 + f4 * 4] = v;
    }
    __syncthreads();

    const int px = tid >> 1, half = tid & 1;
    const float* col = t + (half * 32) * 132 + px;
    unsigned int o[16];
#pragma unroll
    for (int d = 0; d < 16; ++d) {
        float f0 = col[(2 * d) * 132];
        float f1 = col[(2 * d + 1) * 132];
        o[d] = (unsigned int)f2bf(f0) | ((unsigned int)f2bf(f1) << 16);
    }
    unsigned short* dst = xh + ((size_t)(b * 16384 + tile * 128 + px)) * 64 + half * 32;
#pragma unroll
    for (int d = 0; d < 4; ++d)
        *(uint4*)(dst + d * 8) = *(uint4*)&o[d * 4];
}

// ---------------- conv 3x3 + bias + leaky relu: branchless pipelined 9-tap GEMM ----------------
// block: ONE output row x 128 px x 64 co; 4 waves, wave = 32 px x 64 co (2m x 4n).
// A-path branchless: gy clamped (always-valid load) + cndmask zero; dy-grouped
// 1-ahead prefetch (load row dy+1's 6 frags while MFMAing row dy's 12).
// LDS = per-chunk weights, stride 304 (76 dw -> uniform 2-way banks) = 38,912 B.
#define WROW 304
__global__ __launch_bounds__(256, 4) void conv_mfma(const unsigned short* __restrict__ xh,
                                                    const unsigned short* __restrict__ wb,
                                                    const float* __restrict__ cb,
                                                    unsigned short* __restrict__ h) {
    __shared__ unsigned short w_sm[64 * WROW];   // 38,912 B

    // XCD-chunked swizzle: each XCD gets 16 contiguous y rows x all b
    const int id = blockIdx.x;
    const int xcd = id & 7, local = id >> 3;
    const int b = local & 31;
    const int y = (xcd << 4) + (local >> 5);

    const int tid = threadIdx.x;
    const int wave = tid >> 6, lane = tid & 63;
    const int lr = lane & 15, kg = lane >> 4;
    const int px0 = wave * 32;

    f32x4 acc[2][4];
#pragma unroll
    for (int m = 0; m < 2; ++m)
#pragma unroll
        for (int n = 0; n < 4; ++n) acc[m][n] = (f32x4){0.f, 0.f, 0.f, 0.f};

    const unsigned short* bb[4];
#pragma unroll
    for (int n = 0; n < 4; ++n) bb[n] = w_sm + (n * 16 + lr) * WROW + kg * 8;

    const short8 z8 = {0, 0, 0, 0, 0, 0, 0, 0};

    // wave-uniform row validity/clamps (reused across chunks)
    int gyv[3], gyc[3];
#pragma unroll
    for (int r = 0; r < 3; ++r) {
        int gy = y + r - 1;
        gyv[r] = (unsigned)gy < 128u;
        gyc[r] = gy < 0 ? 0 : (gy > 127 ? 127 : gy);
    }
    // per-lane x validity (6 combos, reused everywhere)
    int gxok[2][3];
    int gxi[2][3];
#pragma unroll
    for (int m = 0; m < 2; ++m)
#pragma unroll
        for (int dx = 0; dx < 3; ++dx) {
            int gx = px0 + m * 16 + lr + dx - 1;
            gxok[m][dx] = (unsigned)gx < 128u;
            gxi[m][dx] = (gx & 127) * 64;
        }

    for (int cc = 0; cc < 2; ++cc) {
        __syncthreads();
        // stage chunk-cc weights: source contiguous (j*8), dest stride WROW
        const unsigned short* wsrc = wb + cc * 18432;
        for (int j = tid; j < 2304; j += 256) {
            int q = j & 3, tap = (j >> 2) % 9, co = j / 36;
            *(uint4*)(w_sm + co * WROW + tap * 32 + q * 8) = *(const uint4*)(wsrc + j * 8);
        }
        __syncthreads();

        const unsigned short* xbase = xh + (((size_t)b << 14)) * 64 + cc * 32 + kg * 8;

        short8 L[2][2][3];   // [buf][m][dx], all indices compile-time under unroll

#define LOADSET(BUF, DY)                                                          \
        {                                                                         \
            const unsigned short* rp = xbase + ((size_t)gyc[DY] << 13);           \
            _Pragma("unroll")                                                     \
            for (int m_ = 0; m_ < 2; ++m_) {                                      \
                _Pragma("unroll")                                                 \
                for (int dx_ = 0; dx_ < 3; ++dx_) {                               \
                    short8 v_ = *(const short8*)(rp + gxi[m_][dx_]);              \
                    L[BUF][m_][dx_] = (gyv[DY] && gxok[m_][dx_]) ? v_ : z8;       \
                }                                                                 \
            }                                                                     \
        }

        LOADSET(0, 0)
#pragma unroll
        for (int dy = 0; dy < 3; ++dy) {
            if (dy == 0) LOADSET(1, 1)
            if (dy == 1) LOADSET(0, 2)
#pragma unroll
            for (int dx = 0; dx < 3; ++dx) {
                const int t = dy * 3 + dx;
#pragma unroll
                for (int n = 0; n < 4; ++n) {
                    short8 B = *(const short8*)(bb[n] + t * 32);
                    acc[0][n] = __builtin_amdgcn_mfma_f32_16x16x32_bf16(L[dy & 1][0][dx], B, acc[0][n], 0, 0, 0);
                    acc[1][n] = __builtin_amdgcn_mfma_f32_16x16x32_bf16(L[dy & 1][1][dx], B, acc[1][n], 0, 0, 0);
                }
            }
        }
#undef LOADSET
    }

    // ---- epilogue: bias + leaky relu, bf16 NHWC store ----
    float bias[4];
#pragma unroll
    for (int n = 0; n < 4; ++n) bias[n] = cb[n * 16 + lr];
    const size_t hrow = (size_t)(b * 128 + y) * 128;
#pragma unroll
    for (int m = 0; m < 2; ++m)
#pragma unroll
        for (int rr = 0; rr < 4; ++rr) {
            const int p = px0 + m * 16 + kg * 4 + rr;
            unsigned short* hp = h + (hrow + p) * 64 + lr;
#pragma unroll
            for (int n = 0; n < 4; ++n) {
                float v = acc[m][n][rr] + bias[n];
                v = v > 0.0f ? v : NEG_SLOPE * v;
                hp[n * 16] = f2bf(v);
            }
        }
}

// ---------------- gather + (pairs x 768)·(768 x 24) GEMM via MFMA ----------------
__global__ __launch_bounds__(256) void gather_gemm(const unsigned short* __restrict__ h,
                                                   const int* __restrict__ pos,
                                                   const unsigned short* __restrict__ pw,
                                                   const float* __restrict__ pred_b,
                                                   float* __restrict__ out) {
    __shared__ unsigned char pw_lds[32 * 1536];   // 32 rows x 768 bf16, swizzled
    const int tid = threadIdx.x;

    for (int i = tid; i < 3072; i += 256) {       // 3072 chunks of 16B
        int row = i / 96, c = i - row * 96;
        int dst = row * 1536 + ((c * 16) ^ ((row & 7) << 4));
        *(uint4*)(pw_lds + dst) = ((const uint4*)pw)[i];
    }
    __syncthreads();

    const int wave = tid >> 6, lane = tid & 63;
    const int pair_base = blockIdx.x * 64 + wave * 16;
    const int prow = lane & 15;
    const int kgrp = lane >> 4;
    const int pair = pair_base + prow;
    const int b = pair & 31;
    const unsigned short* hb = h + (size_t)b * 16384 * 64;

    const int swz0 = (prow & 7) << 4;
    const unsigned char* bro0 = pw_lds + prow * 1536;
    const unsigned char* bro1 = pw_lds + (prow + 16) * 1536;

    f32x4 acc0 = {0.f, 0.f, 0.f, 0.f};
    f32x4 acc1 = {0.f, 0.f, 0.f, 0.f};

#pragma unroll
    for (int l = 0; l < 12; ++l) {
        int2 pq = ((const int2*)pos)[pair * 12 + l];
        int px = pq.x < 0 ? 0 : (pq.x > 127 ? 127 : pq.x);
        int py = pq.y < 0 ? 0 : (pq.y > 127 ? 127 : pq.y);
        const unsigned short* pix = hb + (((size_t)py << 7) + px) * 64;
#pragma unroll
        for (int half = 0; half < 2; ++half) {
            const int c0 = half * 32 + kgrp * 8;
            short8 a = *(const short8*)(pix + c0);
            const int kb = (l * 64 + half * 32 + kgrp * 8) * 2;
            short8 b0 = *(const short8*)(bro0 + (kb ^ swz0));
            short8 b1 = *(const short8*)(bro1 + (kb ^ swz0));
            acc0 = __builtin_amdgcn_mfma_f32_16x16x32_bf16(a, b0, acc0, 0, 0, 0);
            acc1 = __builtin_amdgcn_mfma_f32_16x16x32_bf16(a, b1, acc1, 0, 0, 0);
        }
    }

    const int o0 = lane & 15;
    const float bias0 = pred_b[o0];
    const float bias1 = (o0 + 16 < 24) ? pred_b[o0 + 16] : 0.0f;
#pragma unroll
    for (int r = 0; r < 4; ++r) {
        const int pout = pair_base + (lane >> 4) * 4 + r;
        out[(size_t)pout * 24 + o0] = acc0[r] + bias0;
        if (o0 + 16 < 24)
            out[(size_t)pout * 24 + o0 + 16] = acc1[r] + bias1;
    }
}

extern "C" void kernel_launch(void* const* d_in, const int* in_sizes, int n_in,
                              void* d_out, int out_size, void* d_ws, size_t ws_size,
                              hipStream_t stream) {
    const float* x      = (const float*)d_in[0];
    const int*   pos    = (const int*)d_in[1];
    const float* conv_w = (const float*)d_in[2];
    const float* conv_b = (const float*)d_in[3];
    const float* pred_w = (const float*)d_in[4];
    const float* pred_b = (const float*)d_in[5];
    float* out = (float*)d_out;

    char* ws = (char*)d_ws;
    unsigned short* xh  = (unsigned short*)ws;                         // 67,108,864 B
    unsigned short* h   = (unsigned short*)(ws + 67108864);            // 67,108,864 B
    unsigned short* wb  = (unsigned short*)(ws + 134217728);           // 73,728 B
    unsigned short* pwb = (unsigned short*)(ws + 134217728 + 73728);   // 49,152 B

    prep_kernel<<<144, 256, 0, stream>>>(conv_w, pred_w, wb, pwb);
    nchw2nhwc<<<4096, 256, 0, stream>>>(x, xh);
    conv_mfma<<<4096, 256, 0, stream>>>(xh, wb, conv_b, h);
    gather_gemm<<<500, 256, 0, stream>>>(h, pos, pwb, pred_b, out);
}

// Round 10
// 88.075 us; speedup vs baseline: 1.8359x; 1.6852x over previous
//
#include <hip/hip_runtime.h>
#include <hip/hip_bf16.h>

typedef __attribute__((ext_vector_type(8))) short short8;
typedef __attribute__((ext_vector_type(4))) float f32x4;

#define NEG_SLOPE 0.02f

static __device__ __forceinline__ unsigned short f2bf(float f) {
    unsigned int u = __float_as_uint(f);
    u += 0x7fffu + ((u >> 16) & 1u);
    return (unsigned short)(u >> 16);
}

// pack two f32 -> one dword of 2 bf16 (lo, hi) via v_cvt_pk_bf16_f32
static __device__ __forceinline__ unsigned int pk2bf(float lo, float hi) {
    __hip_bfloat162 t = __float22bfloat162_rn(float2{lo, hi});
    unsigned int u;
    __builtin_memcpy(&u, &t, 4);
    return u;
}

// ---------------- prep: weight transforms ----------------
// wb chunk-major: [cc][co][tap][ci32]  bf16  (2*64*9*32) from conv_w[co][ci][dy][dx]
// pwb[o][k] = bf16(pred_w[o][k]) for o<24, 0 pad to 32 rows  (32*768 bf16)
__global__ __launch_bounds__(256) void prep_kernel(const float* __restrict__ conv_w,
                                                   const float* __restrict__ pred_w,
                                                   unsigned short* __restrict__ wb,
                                                   unsigned short* __restrict__ pwb) {
    int i = blockIdx.x * 256 + threadIdx.x;
    if (i < 36864) {
        int ci5 = i & 31, tap = (i >> 5) % 9, rest = i / 288;  // rest = cc*64 + co
        int co = rest & 63, cc = rest >> 6;
        int ci = cc * 32 + ci5;
        wb[i] = f2bf(conv_w[(co * 64 + ci) * 9 + tap]);
    }
    if (i < 24576) {
        int o = i / 768, k = i - o * 768;
        pwb[i] = f2bf(o < 24 ? pred_w[o * 768 + k] : 0.0f);
    }
}

// ---------------- fused conv 3x3 + bias + leaky relu (NCHW f32 in, NHWC bf16 out) ----------------
// block: 512 thr = 8 waves; 2 output rows x 128 px x 64 co. wave = 32 px x 64 co (2m x 4n).
// LDS: per-chunk weights [64co][304] (38,912 B) + input 4 rows x 65 pairs x 128 B (33,280 B)
//      = 72,192 B -> 2 blocks/CU, 4 waves/SIMD with __launch_bounds__(512,4).
// Staging (per chunk, per row r): thread -> (pair = wave*8 + (lane>>3), odd, q);
//   8 coalesced f32 loads of x[ci..ci+7][gy][gx] -> 4 cvt_pk -> ONE ds_write_b128 at
//   [r][pair][slot], slot = ((odd<<2)|q) ^ (pair&7). Wave covers pairs wave*8..+7 x all
//   8 slots = 1 KB contiguous -> conflict-free. xx=0 pad folded in (gx<0 -> zeros);
//   xx=128,129 staged by a 32-lane tail pass.
#define ROW_BYTES 8320   // 65 pairs * 128
#define WROW 304
__global__ __launch_bounds__(512, 4) void conv_mfma(const float* __restrict__ x,
                                                    const unsigned short* __restrict__ wb,
                                                    const float* __restrict__ cb,
                                                    unsigned short* __restrict__ h) {
    __shared__ unsigned short w_sm[64 * WROW];       // 38,912 B
    __shared__ unsigned char in_sm[4 * ROW_BYTES];   // 33,280 B

    // XCD-chunked swizzle: each XCD owns 16 contiguous y rows (8 y-pairs) x all b
    const int id = blockIdx.x;                       // 2048 blocks
    const int xcd = id & 7, local = id >> 3;
    const int b = local & 31;
    const int y0 = ((xcd << 3) + (local >> 5)) * 2;

    const int tid = threadIdx.x;
    const int wave = tid >> 6, lane = tid & 63;
    const int lr = lane & 15, kg = lane >> 4;
    const int ro = wave >> 2;                        // output row within block (0/1)
    const int px0 = (wave & 3) * 32;                 // px quarter

    f32x4 acc[2][4];
#pragma unroll
    for (int m = 0; m < 2; ++m)
#pragma unroll
        for (int n = 0; n < 4; ++n) acc[m][n] = (f32x4){0.f, 0.f, 0.f, 0.f};

    // A-frag base offsets (proven pair/slot swizzle), (ro+dy)*ROW_BYTES added at use
    const unsigned char* ab[2][3];
#pragma unroll
    for (int m = 0; m < 2; ++m)
#pragma unroll
        for (int dx = 0; dx < 3; ++dx) {
            int xx = px0 + m * 16 + lr + dx;         // 0..129
            int pair = xx >> 1, odd = xx & 1;
            int slot = ((odd << 2) | kg) ^ (pair & 7);
            ab[m][dx] = in_sm + pair * 128 + slot * 16;
        }
    const unsigned short* bbp[4];
#pragma unroll
    for (int n = 0; n < 4; ++n) bbp[n] = w_sm + (n * 16 + lr) * WROW + kg * 8;

    // staging lane geometry (constant across chunks/rows)
    const int s_pair = wave * 8 + (lane >> 3);       // 0..63
    const int s_odd = (lane >> 2) & 1, s_q = lane & 3;
    const int s_xx = s_pair * 2 + s_odd;             // 0..127
    const int s_gx = s_xx - 1;                       // -1..126
    const int s_gxc = s_gx < 0 ? 0 : s_gx;
    const int s_slot = ((s_odd << 2) | s_q) ^ (s_pair & 7);
    const int s_dst = s_pair * 128 + s_slot * 16;

    for (int cc = 0; cc < 2; ++cc) {
        __syncthreads();
        // ---- stage weights: dest [co][tap*32+q*8] stride WROW, src contiguous ----
        const unsigned short* wsrc = wb + cc * 18432;
        for (int j = tid; j < 2304; j += 512) {
            int q = j & 3, tap = (j >> 2) % 9, co = j / 36;
            *(uint4*)(w_sm + co * WROW + tap * 32 + q * 8) = *(const uint4*)(wsrc + j * 8);
        }
        // ---- stage input: 4 rows, conflict-free pair-block writes ----
        const float* xc = x + ((size_t)b * 64 + cc * 32 + s_q * 8) * 16384;
#pragma unroll
        for (int r = 0; r < 4; ++r) {
            int gy = y0 + r - 1;
            uint4 d = {0u, 0u, 0u, 0u};
            if ((unsigned)gy < 128u) {
                const float* src = xc + gy * 128 + s_gxc;
                float f[8];
#pragma unroll
                for (int c = 0; c < 8; ++c) f[c] = src[(size_t)c * 16384];
                if (s_gx >= 0) {
                    d.x = pk2bf(f[0], f[1]); d.y = pk2bf(f[2], f[3]);
                    d.z = pk2bf(f[4], f[5]); d.w = pk2bf(f[6], f[7]);
                }
            }
            *(uint4*)(in_sm + r * ROW_BYTES + s_dst) = d;
        }
        // ---- tail: xx = 128 (gx=127) and xx = 129 (zero pad) ----
        if (tid < 32) {
            int q = tid & 3, odd = (tid >> 2) & 1, r = tid >> 3;
            int gy = y0 + r - 1;
            uint4 d = {0u, 0u, 0u, 0u};
            if (odd == 0 && (unsigned)gy < 128u) {
                const float* src = x + ((size_t)b * 64 + cc * 32 + q * 8) * 16384 + gy * 128 + 127;
                float f[8];
#pragma unroll
                for (int c = 0; c < 8; ++c) f[c] = src[(size_t)c * 16384];
                d.x = pk2bf(f[0], f[1]); d.y = pk2bf(f[2], f[3]);
                d.z = pk2bf(f[4], f[5]); d.w = pk2bf(f[6], f[7]);
            }
            int slot = ((odd << 2) | q);             // pair 64 -> pair&7 == 0
            *(uint4*)(in_sm + r * ROW_BYTES + 64 * 128 + slot * 16) = d;
        }
        __syncthreads();

        // ---- compute: 9 taps x (4n x 2m) MFMA, A/B from LDS ----
#pragma unroll
        for (int t = 0; t < 9; ++t) {
            const int dy = t / 3, dx = t % 3;
            const int aoff = (ro + dy) * ROW_BYTES;
            short8 A0 = *(const short8*)(ab[0][dx] + aoff);
            short8 A1 = *(const short8*)(ab[1][dx] + aoff);
#pragma unroll
            for (int n = 0; n < 4; ++n) {
                short8 B = *(const short8*)(bbp[n] + t * 32);
                acc[0][n] = __builtin_amdgcn_mfma_f32_16x16x32_bf16(A0, B, acc[0][n], 0, 0, 0);
                acc[1][n] = __builtin_amdgcn_mfma_f32_16x16x32_bf16(A1, B, acc[1][n], 0, 0, 0);
            }
        }
    }

    // ---- epilogue: bias + leaky relu, bf16 NHWC store ----
    float bias[4];
#pragma unroll
    for (int n = 0; n < 4; ++n) bias[n] = cb[n * 16 + lr];
    const int y = y0 + ro;
    const size_t hrow = (size_t)(b * 128 + y) * 128;
#pragma unroll
    for (int m = 0; m < 2; ++m)
#pragma unroll
        for (int rr = 0; rr < 4; ++rr) {
            const int p = px0 + m * 16 + kg * 4 + rr;
            unsigned short* hp = h + (hrow + p) * 64 + lr;
#pragma unroll
            for (int n = 0; n < 4; ++n) {
                float v = acc[m][n][rr] + bias[n];
                v = v > 0.0f ? v : NEG_SLOPE * v;
                hp[n * 16] = f2bf(v);
            }
        }
}

// ---------------- gather + (pairs x 768)·(768 x 24) GEMM via MFMA ----------------
__global__ __launch_bounds__(256) void gather_gemm(const unsigned short* __restrict__ h,
                                                   const int* __restrict__ pos,
                                                   const unsigned short* __restrict__ pw,
                                                   const float* __restrict__ pred_b,
                                                   float* __restrict__ out) {
    __shared__ unsigned char pw_lds[32 * 1536];   // 32 rows x 768 bf16, swizzled
    const int tid = threadIdx.x;

    for (int i = tid; i < 3072; i += 256) {       // 3072 chunks of 16B
        int row = i / 96, c = i - row * 96;
        int dst = row * 1536 + ((c * 16) ^ ((row & 7) << 4));
        *(uint4*)(pw_lds + dst) = ((const uint4*)pw)[i];
    }
    __syncthreads();

    const int wave = tid >> 6, lane = tid & 63;
    const int pair_base = blockIdx.x * 64 + wave * 16;
    const int prow = lane & 15;
    const int kgrp = lane >> 4;
    const int pair = pair_base + prow;
    const int b = pair & 31;
    const unsigned short* hb = h + (size_t)b * 16384 * 64;

    const int swz0 = (prow & 7) << 4;
    const unsigned char* bro0 = pw_lds + prow * 1536;
    const unsigned char* bro1 = pw_lds + (prow + 16) * 1536;

    f32x4 acc0 = {0.f, 0.f, 0.f, 0.f};
    f32x4 acc1 = {0.f, 0.f, 0.f, 0.f};

#pragma unroll
    for (int l = 0; l < 12; ++l) {
        int2 pq = ((const int2*)pos)[pair * 12 + l];
        int px = pq.x < 0 ? 0 : (pq.x > 127 ? 127 : pq.x);
        int py = pq.y < 0 ? 0 : (pq.y > 127 ? 127 : pq.y);
        const unsigned short* pix = hb + (((size_t)py << 7) + px) * 64;
#pragma unroll
        for (int half = 0; half < 2; ++half) {
            const int c0 = half * 32 + kgrp * 8;
            short8 a = *(const short8*)(pix + c0);
            const int kb = (l * 64 + half * 32 + kgrp * 8) * 2;
            short8 b0 = *(const short8*)(bro0 + (kb ^ swz0));
            short8 b1 = *(const short8*)(bro1 + (kb ^ swz0));
            acc0 = __builtin_amdgcn_mfma_f32_16x16x32_bf16(a, b0, acc0, 0, 0, 0);
            acc1 = __builtin_amdgcn_mfma_f32_16x16x32_bf16(a, b1, acc1, 0, 0, 0);
        }
    }

    const int o0 = lane & 15;
    const float bias0 = pred_b[o0];
    const float bias1 = (o0 + 16 < 24) ? pred_b[o0 + 16] : 0.0f;
#pragma unroll
    for (int r = 0; r < 4; ++r) {
        const int pout = pair_base + (lane >> 4) * 4 + r;
        out[(size_t)pout * 24 + o0] = acc0[r] + bias0;
        if (o0 + 16 < 24)
            out[(size_t)pout * 24 + o0 + 16] = acc1[r] + bias1;
    }
}

extern "C" void kernel_launch(void* const* d_in, const int* in_sizes, int n_in,
                              void* d_out, int out_size, void* d_ws, size_t ws_size,
                              hipStream_t stream) {
    const float* x      = (const float*)d_in[0];
    const int*   pos    = (const int*)d_in[1];
    const float* conv_w = (const float*)d_in[2];
    const float* conv_b = (const float*)d_in[3];
    const float* pred_w = (const float*)d_in[4];
    const float* pred_b = (const float*)d_in[5];
    float* out = (float*)d_out;

    char* ws = (char*)d_ws;
    unsigned short* h   = (unsigned short*)ws;                        // 67,108,864 B
    unsigned short* wb  = (unsigned short*)(ws + 67108864);           // 73,728 B
    unsigned short* pwb = (unsigned short*)(ws + 67108864 + 73728);   // 49,152 B

    prep_kernel<<<144, 256, 0, stream>>>(conv_w, pred_w, wb, pwb);
    conv_mfma<<<2048, 512, 0, stream>>>(x, wb, conv_b, h);
    gather_gemm<<<500, 256, 0, stream>>>(h, pos, pwb, pred_b, out);
}